// Round 1
// baseline (1229.017 us; speedup 1.0000x reference)
//
#include <hip/hip_runtime.h>
#include <math.h>

#define BS 32
#define NI 196
#define NT 256
#define DD 1024

typedef unsigned int u32;

// monotonic float<->uint mapping for atomic min/max over possibly-negative floats
__device__ __forceinline__ u32 fenc(float f){ u32 u = __float_as_uint(f); return (u & 0x80000000u) ? ~u : (u | 0x80000000u); }
__device__ __forceinline__ float fdec(u32 u){ return __uint_as_float((u & 0x80000000u) ? (u & 0x7fffffffu) : ~u); }

// ---------------- init min/max slots ----------------
__global__ void init_mm_k(u32* mm){
  int t = threadIdx.x;
  if (t < 3){ mm[2*t] = 0xFFFFFFFFu; mm[2*t+1] = 0u; }
}

// ---------------- per-row normalization scales ----------------
// scale[b,r] = mask / (mask*||row|| + 1e-12)  (mask==nullptr -> 1)
__global__ __launch_bounds__(256) void row_scale_k(const float* __restrict__ feat,
                                                   const float* __restrict__ mask,
                                                   float* __restrict__ scale, int R){
  int b = blockIdx.y, r = blockIdx.x, t = threadIdx.x;
  const float4* row = (const float4*)(feat + ((size_t)b*R + r)*DD);
  float4 v = row[t];
  float s = v.x*v.x + v.y*v.y + v.z*v.z + v.w*v.w;
  #pragma unroll
  for (int m = 32; m >= 1; m >>= 1) s += __shfl_xor(s, m);
  __shared__ float ps[4];
  if ((t & 63) == 0) ps[t >> 6] = s;
  __syncthreads();
  if (t == 0){
    float tot = ps[0] + ps[1] + ps[2] + ps[3];
    float mv = mask ? mask[b*R + r] : 1.0f;
    float nrm = mv * sqrtf(tot);
    scale[b*R + r] = mv / (nrm + 1e-12f);
  }
}

// ---------------- batched GEMM ----------------
// TRB=true : C[r,c] = sum_k A[r,k]*B[c,k]   (A:MxK, B:NxK)
// TRB=false: C[r,c] = sum_k A[r,k]*B[k,c]   (A:MxK, B:KxN)
// optional per-row scales sA[b*M+r], sB[b*N+c] applied to loads
// EPI: 0 plain, 1 -> 1-x, 2 -> av[r]+bv[c]-2x
template<bool TRB, int EPI>
__global__ __launch_bounds__(256) void gemm_k(const float* __restrict__ A,
                                              const float* __restrict__ B,
                                              float* __restrict__ C,
                                              int M, int N, int K,
                                              const float* __restrict__ sA,
                                              const float* __restrict__ sB,
                                              const float* __restrict__ av,
                                              const float* __restrict__ bv){
  __shared__ float As[16][68];
  __shared__ float Bs[16][68];
  int b  = blockIdx.z;
  int r0 = blockIdx.x * 64;
  int c0 = blockIdx.y * 64;
  int t  = threadIdx.x;
  int tx = t & 15, ty = t >> 4;
  const float* Ab = A + (size_t)b * M * K;
  const float* Bb = B + (size_t)b * (size_t)N * K;
  float acc[4][4] = {{0.f}};
  int lr = t >> 2, lq = t & 3;
  for (int k0 = 0; k0 < K; k0 += 16){
    { // A tile (transposed store)
      int gr = r0 + lr, kk = k0 + lq*4;
      float4 v = make_float4(0.f,0.f,0.f,0.f);
      if (gr < M && kk + 3 < K) v = *(const float4*)(Ab + (size_t)gr*K + kk);
      if (sA && gr < M){ float s = sA[b*M + gr]; v.x*=s; v.y*=s; v.z*=s; v.w*=s; }
      As[lq*4+0][lr]=v.x; As[lq*4+1][lr]=v.y; As[lq*4+2][lr]=v.z; As[lq*4+3][lr]=v.w;
    }
    if (TRB){
      int gc = c0 + lr, kk = k0 + lq*4;
      float4 v = make_float4(0.f,0.f,0.f,0.f);
      if (gc < N && kk + 3 < K) v = *(const float4*)(Bb + (size_t)gc*K + kk);
      if (sB && gc < N){ float s = sB[b*N + gc]; v.x*=s; v.y*=s; v.z*=s; v.w*=s; }
      Bs[lq*4+0][lr]=v.x; Bs[lq*4+1][lr]=v.y; Bs[lq*4+2][lr]=v.z; Bs[lq*4+3][lr]=v.w;
    } else {
      int kr = t >> 4, cx = (t & 15) * 4;
      int gk = k0 + kr, gc = c0 + cx;
      float4 v = make_float4(0.f,0.f,0.f,0.f);
      if (gk < K && gc + 3 < N) v = *(const float4*)(Bb + (size_t)gk*N + gc);
      *(float4*)&Bs[kr][cx] = v;
    }
    __syncthreads();
    #pragma unroll
    for (int kk = 0; kk < 16; ++kk){
      float4 a4 = *(const float4*)&As[kk][ty*4];
      float4 b4 = *(const float4*)&Bs[kk][tx*4];
      float aa[4] = {a4.x, a4.y, a4.z, a4.w};
      float bb[4] = {b4.x, b4.y, b4.z, b4.w};
      #pragma unroll
      for (int i = 0; i < 4; ++i)
        #pragma unroll
        for (int j = 0; j < 4; ++j)
          acc[i][j] = fmaf(aa[i], bb[j], acc[i][j]);
    }
    __syncthreads();
  }
  #pragma unroll
  for (int i = 0; i < 4; ++i){
    int r = r0 + ty*4 + i;
    if (r >= M) continue;
    #pragma unroll
    for (int j = 0; j < 4; ++j){
      int cc = c0 + tx*4 + j;
      if (cc >= N) continue;
      float x = acc[i][j];
      if (EPI == 1) x = 1.0f - x;
      else if (EPI == 2) x = av[b*M + r] + bv[b*N + cc] - 2.0f*x;
      C[(size_t)b*M*N + (size_t)r*N + cc] = x;
    }
  }
}

// ---------------- global min/max ----------------
__global__ __launch_bounds__(256) void minmax_k(const float* __restrict__ X, size_t cnt, u32* __restrict__ mm){
  size_t stride = (size_t)gridDim.x * blockDim.x;
  float mn = 3.402823466e38f, mx = -3.402823466e38f;
  for (size_t i = (size_t)blockIdx.x*blockDim.x + threadIdx.x; i < cnt; i += stride){
    float v = X[i]; mn = fminf(mn, v); mx = fmaxf(mx, v);
  }
  #pragma unroll
  for (int m = 32; m >= 1; m >>= 1){ mn = fminf(mn, __shfl_xor(mn, m)); mx = fmaxf(mx, __shfl_xor(mx, m)); }
  __shared__ float smn[4], smx[4];
  int t = threadIdx.x;
  if ((t & 63) == 0){ smn[t>>6] = mn; smx[t>>6] = mx; }
  __syncthreads();
  if (t == 0){
    mn = fminf(fminf(smn[0], smn[1]), fminf(smn[2], smn[3]));
    mx = fmaxf(fmaxf(smx[0], smx[1]), fmaxf(smx[2], smx[3]));
    atomicMin(&mm[0], fenc(mn));
    atomicMax(&mm[1], fenc(mx));
  }
}

// ---------------- threshold-relu (+ optional {0,1}->{1e-5,1} mask) ----------------
__global__ __launch_bounds__(256) void thresh_k(float* __restrict__ X, const int* __restrict__ msk,
                                                size_t cnt, const u32* __restrict__ mm){
  float mn = fdec(mm[0]), mx = fdec(mm[1]);
  float thr = mn + 0.1f * (mx - mn);
  size_t stride = (size_t)gridDim.x * blockDim.x;
  for (size_t i = (size_t)blockIdx.x*blockDim.x + threadIdx.x; i < cnt; i += stride){
    float v = X[i] - thr;
    v = v > 0.f ? v : 0.f;
    if (msk) v *= (msk[i] == 1 ? 1.0f : 1e-5f);
    X[i] = v;
  }
}

// ---------------- row mean of squares ----------------
__global__ __launch_bounds__(64) void rowmeansq_k(const float* __restrict__ X, float* __restrict__ out, int R, int Cc){
  int b = blockIdx.y, r = blockIdx.x, t = threadIdx.x;
  const float* row = X + ((size_t)b*R + r) * Cc;
  float s = 0.f;
  for (int j = t; j < Cc; j += 64){ float v = row[j]; s = fmaf(v, v, s); }
  #pragma unroll
  for (int m = 32; m >= 1; m >>= 1) s += __shfl_xor(s, m);
  if (t == 0) out[b*R + r] = s / (float)Cc;
}

// ---------------- fill ----------------
__global__ void fill_k(float* __restrict__ X, size_t cnt, float val){
  size_t stride = (size_t)gridDim.x * blockDim.x;
  for (size_t i = (size_t)blockIdx.x*blockDim.x + threadIdx.x; i < cnt; i += stride) X[i] = val;
}

// ---------------- IPOT: 20 proximal iterations, whole P and T in registers ----------------
// one block (512 threads) per batch item. thread (R=t>>5 in 0..15, c=t&31),
// rows i=R+16k (k<13, masked i<NI), cols j=c+32l (l<8).
template<bool WD>
__global__ __launch_bounds__(512) void ipot_k(const float* __restrict__ Cmat,
                                              float* __restrict__ Tout,
                                              float* __restrict__ distBuf){
  __shared__ float cp[16][NT];
  __shared__ float sgm[NT];
  int b = blockIdx.x, t = threadIdx.x;
  int c = t & 31, R = t >> 5;
  const float* Cb = Cmat + (size_t)b * NI * NT;
  float P[13][8], T[13][8];
  #pragma unroll
  for (int k = 0; k < 13; ++k){
    int i = R + 16*k;
    bool ok = (i < NI);
    #pragma unroll
    for (int l = 0; l < 8; ++l){
      int j = c + 32*l;
      float Cv = ok ? Cb[(size_t)i*NT + j] : 0.f;
      P[k][l] = ok ? expf(-2.0f * Cv) : 0.f;   // A = exp(-C/beta), beta=0.5
      T[k][l] = ok ? 1.f : 0.f;
    }
  }
  float sl[8];
  #pragma unroll
  for (int l = 0; l < 8; ++l) sl[l] = 1.0f / (float)NT;

  for (int it = 0; it < 20; ++it){
    // Q = P*T (stored into T); row sums r_i = sum_j Q_ij * sigma_j
    float rp[13];
    #pragma unroll
    for (int k = 0; k < 13; ++k){
      float a = 0.f;
      #pragma unroll
      for (int l = 0; l < 8; ++l){
        float q = P[k][l] * T[k][l];
        T[k][l] = q;
        a = fmaf(q, sl[l], a);
      }
      rp[k] = a;
    }
    // butterfly over the 32 col-threads (lane bits 0..4)
    #pragma unroll
    for (int m = 1; m <= 16; m <<= 1){
      #pragma unroll
      for (int k = 0; k < 13; ++k) rp[k] += __shfl_xor(rp[k], m);
    }
    float dl[13];
    #pragma unroll
    for (int k = 0; k < 13; ++k){
      int i = R + 16*k;
      dl[k] = (i < NI) ? 1.0f / ((float)NI * rp[k]) : 0.f;   // delta_i
    }
    // col partials: c_j = sum_i Q_ij * delta_i
    float cpl[8];
    #pragma unroll
    for (int l = 0; l < 8; ++l) cpl[l] = 0.f;
    #pragma unroll
    for (int k = 0; k < 13; ++k)
      #pragma unroll
      for (int l = 0; l < 8; ++l) cpl[l] = fmaf(T[k][l], dl[k], cpl[l]);
    #pragma unroll
    for (int l = 0; l < 8; ++l) cp[R][c + 32*l] = cpl[l];
    __syncthreads();
    if (t < NT){
      float s = 0.f;
      #pragma unroll
      for (int g = 0; g < 16; ++g) s += cp[g][t];
      sgm[t] = 1.0f / ((float)NT * s);                        // sigma_j
    }
    __syncthreads();
    #pragma unroll
    for (int l = 0; l < 8; ++l) sl[l] = sgm[c + 32*l];
    // T = delta * Q * sigma
    #pragma unroll
    for (int k = 0; k < 13; ++k){
      #pragma unroll
      for (int l = 0; l < 8; ++l) T[k][l] *= dl[k] * sl[l];
    }
  }
  float* To = Tout + (size_t)b * NI * NT;
  #pragma unroll
  for (int k = 0; k < 13; ++k){
    int i = R + 16*k;
    if (i < NI){
      #pragma unroll
      for (int l = 0; l < 8; ++l) To[(size_t)i*NT + c + 32*l] = T[k][l];
    }
  }
  if (WD){
    float a = 0.f;
    #pragma unroll
    for (int k = 0; k < 13; ++k){
      int i = R + 16*k;
      if (i < NI){
        #pragma unroll
        for (int l = 0; l < 8; ++l) a = fmaf(Cb[(size_t)i*NT + c + 32*l], T[k][l], a);
      }
    }
    #pragma unroll
    for (int m = 32; m >= 1; m >>= 1) a += __shfl_xor(a, m);
    __shared__ float wp[8];
    if ((t & 63) == 0) wp[t >> 6] = a;
    __syncthreads();
    if (t == 0){
      float s = 0.f;
      #pragma unroll
      for (int g = 0; g < 8; ++g) s += wp[g];
      distBuf[b] = -s;    // wd = -sum(C*T)
    }
  }
}

// ---------------- GW final distance + copy gamma to output ----------------
__global__ __launch_bounds__(256) void gwdist_k(const float* __restrict__ Cg, const float* __restrict__ gam,
                                                float* __restrict__ outT, float* __restrict__ gwd){
  int b = blockIdx.x, t = threadIdx.x;
  const float* cb = Cg + (size_t)b*NI*NT;
  const float* gb = gam + (size_t)b*NI*NT;
  float* ob = outT + (size_t)b*NI*NT;
  float a = 0.f;
  for (int i = t; i < NI*NT; i += 256){
    float g = gb[i];
    a = fmaf(cb[i], g, a);
    ob[i] = g;
  }
  #pragma unroll
  for (int m = 32; m >= 1; m >>= 1) a += __shfl_xor(a, m);
  __shared__ float ps[4];
  if ((t & 63) == 0) ps[t>>6] = a;
  __syncthreads();
  if (t == 0) gwd[b] = ps[0]+ps[1]+ps[2]+ps[3];
}

// ---------------- final scalar ----------------
__global__ void fin_k(const float* __restrict__ wd, const float* __restrict__ gwd, float* __restrict__ out){
  int t = threadIdx.x;
  float w = (t < BS) ? wd[t] : 0.f;
  float g = (t < BS) ? gwd[t] : 0.f;
  #pragma unroll
  for (int m = 32; m >= 1; m >>= 1){ w += __shfl_xor(w, m); g += __shfl_xor(g, m); }
  if (t == 0) out[0] = 0.1f * (g / (float)BS) + 0.1f * (w / (float)BS);
}

extern "C" void kernel_launch(void* const* d_in, const int* in_sizes, int n_in,
                              void* d_out, int out_size, void* d_ws, size_t ws_size,
                              hipStream_t stream){
  const float* img  = (const float*)d_in[0];   // (32,196,1024)
  const float* tok  = (const float*)d_in[1];   // (32,256,1024)
  const float* tmsk = (const float*)d_in[2];   // (32,256)
  const int*   tdm  = (const int*)d_in[3];     // (32,256,256)
  const int*   irm  = (const int*)d_in[4];     // (32,196,196)
  float* out = (float*)d_out;                  // [twd, T_wd(32*196*256), T_gwd(32*196*256)]

  float* ws = (float*)d_ws;
  size_t off = 0;
  float* scale_img = ws + off; off += (size_t)BS*NI;
  float* scale_tok = ws + off; off += (size_t)BS*NT;
  float* cosIT = ws + off; off += (size_t)BS*NI*NT;
  float* Cs    = ws + off; off += (size_t)BS*NI*NI;
  float* Ct    = ws + off; off += (size_t)BS*NT*NT;
  float* gamma = ws + off; off += (size_t)BS*NI*NT;
  float* Cgam  = ws + off; off += (size_t)BS*NI*NT;
  float* G1    = ws + off; off += (size_t)BS*NI*NT;
  float* avec  = ws + off; off += (size_t)BS*NI;
  float* bvec  = ws + off; off += (size_t)BS*NT;
  u32*   mm    = (u32*)(ws + off); off += 8;
  float* wd_b  = ws + off; off += BS;
  float* gwd_b = ws + off; off += BS;

  init_mm_k<<<1, 64, 0, stream>>>(mm);
  row_scale_k<<<dim3(NI,BS), 256, 0, stream>>>(img, nullptr, scale_img, NI);
  row_scale_k<<<dim3(NT,BS), 256, 0, stream>>>(tok, tmsk, scale_tok, NT);

  // cosine cost matrices (1 - dot of normalized rows)
  gemm_k<true,1><<<dim3((NI+63)/64,(NT+63)/64,BS), 256, 0, stream>>>(img, tok, cosIT, NI, NT, DD, scale_img, scale_tok, nullptr, nullptr);
  gemm_k<true,1><<<dim3((NI+63)/64,(NI+63)/64,BS), 256, 0, stream>>>(img, img, Cs, NI, NI, DD, scale_img, scale_img, nullptr, nullptr);
  gemm_k<true,1><<<dim3((NT+63)/64,(NT+63)/64,BS), 256, 0, stream>>>(tok, tok, Ct, NT, NT, DD, scale_tok, scale_tok, nullptr, nullptr);

  // global min/max then threshold-relu (+mask for Cs/Ct)
  minmax_k<<<512, 256, 0, stream>>>(cosIT, (size_t)BS*NI*NT, mm+0);
  minmax_k<<<512, 256, 0, stream>>>(Cs,    (size_t)BS*NI*NI, mm+2);
  minmax_k<<<512, 256, 0, stream>>>(Ct,    (size_t)BS*NT*NT, mm+4);
  thresh_k<<<1024, 256, 0, stream>>>(cosIT, nullptr, (size_t)BS*NI*NT, mm+0);
  thresh_k<<<1024, 256, 0, stream>>>(Cs,    irm,     (size_t)BS*NI*NI, mm+2);
  thresh_k<<<1024, 256, 0, stream>>>(Ct,    tdm,     (size_t)BS*NT*NT, mm+4);

  // Cst components: avec_i = mean_k Cs_ik^2 ; bvec_j = mean_l Ct_jl^2
  rowmeansq_k<<<dim3(NI,BS), 64, 0, stream>>>(Cs, avec, NI, NI);
  rowmeansq_k<<<dim3(NT,BS), 64, 0, stream>>>(Ct, bvec, NT, NT);

  // wd = -sum(C*T) with T = IPOT(cos_dist, 20); writes T_wd
  ipot_k<true><<<BS, 512, 0, stream>>>(cosIT, out + 1, wd_b);

  // GW: gamma0 = 1/(n*m)
  fill_k<<<512, 256, 0, stream>>>(gamma, (size_t)BS*NI*NT, 1.0f/((float)NI*(float)NT));
  for (int itn = 0; itn < 6; ++itn){
    // G1 = Cs @ gamma   (NN)
    gemm_k<false,0><<<dim3((NI+63)/64,(NT+63)/64,BS), 256, 0, stream>>>(Cs, gamma, G1, NI, NT, NI, nullptr, nullptr, nullptr, nullptr);
    // Cgam = avec_i + bvec_j - 2 * G1 @ Ct^T   (einsum contracts Ct's 2nd index)
    gemm_k<true,2><<<dim3((NI+63)/64,(NT+63)/64,BS), 256, 0, stream>>>(G1, Ct, Cgam, NI, NT, NT, nullptr, nullptr, avec, bvec);
    if (itn < 5)
      ipot_k<false><<<BS, 512, 0, stream>>>(Cgam, gamma, nullptr);
  }

  // gwd_b = sum(Cgam * gamma), and T_gwd = gamma
  gwdist_k<<<BS, 256, 0, stream>>>(Cgam, gamma, out + 1 + (size_t)BS*NI*NT, gwd_b);
  fin_k<<<1, 64, 0, stream>>>(wd_b, gwd_b, out);
}